// Round 1
// baseline (1372.005 us; speedup 1.0000x reference)
//
#include <hip/hip_runtime.h>

// ---------------------------------------------------------------------------
// MambaDecoderLayer fused implementation for MI355X (gfx950)
// Shapes: B=2, L=1024 (rows=2048), D_MODEL=2048, D_INNER=2048, D_XB=512,
// D_STATE=32, DT_RANK=128, D_FF=5632, proj_dim=5248
// ---------------------------------------------------------------------------

typedef __attribute__((ext_vector_type(4))) float f32x4;
typedef __attribute__((ext_vector_type(8))) __bf16 bf16x8;

__device__ __forceinline__ unsigned short f2b(float f) {
  unsigned u = __builtin_bit_cast(unsigned, f);
  u += 0x7fffu + ((u >> 16) & 1u);          // round-to-nearest-even
  return (unsigned short)(u >> 16);
}
__device__ __forceinline__ float b2f(unsigned short b) {
  return __builtin_bit_cast(float, ((unsigned)b) << 16);
}

// ---------------------------------------------------------------------------
// fp32 -> bf16 bulk convert (pairs)
// ---------------------------------------------------------------------------
__global__ __launch_bounds__(256) void cvt_bf16(const float2* __restrict__ in,
                                                unsigned int* __restrict__ out,
                                                int n2) {
  int i = blockIdx.x * 256 + threadIdx.x;
  if (i >= n2) return;
  float2 v = in[i];
  out[i] = (unsigned)f2b(v.x) | ((unsigned)f2b(v.y) << 16);
}

// ---------------------------------------------------------------------------
// RMSNorm (rows of 2048) -> bf16 output
// ---------------------------------------------------------------------------
__global__ __launch_bounds__(256) void rmsnorm_cast(const float* __restrict__ x,
                                                    const float* __restrict__ w,
                                                    unsigned short* __restrict__ out) {
  int row = blockIdx.x;
  int t = threadIdx.x;
  const float* xr = x + (size_t)row * 2048;
  float4 v0 = *(const float4*)&xr[t * 8];
  float4 v1 = *(const float4*)&xr[t * 8 + 4];
  float s = v0.x * v0.x + v0.y * v0.y + v0.z * v0.z + v0.w * v0.w +
            v1.x * v1.x + v1.y * v1.y + v1.z * v1.z + v1.w * v1.w;
#pragma unroll
  for (int off = 1; off < 64; off <<= 1) s += __shfl_xor(s, off);
  __shared__ float red[4];
  if ((t & 63) == 0) red[t >> 6] = s;
  __syncthreads();
  s = red[0] + red[1] + red[2] + red[3];
  float scale = rsqrtf(s * (1.0f / 2048.0f) + 1e-5f);
  float4 w0 = *(const float4*)&w[t * 8];
  float4 w1 = *(const float4*)&w[t * 8 + 4];
  uint4 o;
  o.x = (unsigned)f2b(v0.x * scale * w0.x) | ((unsigned)f2b(v0.y * scale * w0.y) << 16);
  o.y = (unsigned)f2b(v0.z * scale * w0.z) | ((unsigned)f2b(v0.w * scale * w0.w) << 16);
  o.z = (unsigned)f2b(v1.x * scale * w1.x) | ((unsigned)f2b(v1.y * scale * w1.y) << 16);
  o.w = (unsigned)f2b(v1.z * scale * w1.z) | ((unsigned)f2b(v1.w * scale * w1.w) << 16);
  *(uint4*)&out[(size_t)row * 2048 + t * 8] = o;
}

// ---------------------------------------------------------------------------
// Extract dt_raw slice of zxbcdt (cols 5120..5248) -> bf16 [2048,128]
// ---------------------------------------------------------------------------
__global__ __launch_bounds__(256) void cast_dtraw(const float* __restrict__ zx,
                                                  unsigned short* __restrict__ dst) {
  int i = blockIdx.x * 256 + threadIdx.x;  // 0..262143
  int r = i >> 7, c = i & 127;
  dst[i] = f2b(zx[(size_t)r * 5248 + 5120 + c]);
}

// ---------------------------------------------------------------------------
// bf16 MFMA GEMM, out[m,n] = sum_k A[m,k] * W[n,k]  (W row-major [N,K])
// 128x128 tile, BK=64, 4 waves (2x2), global_load_lds staging with XOR-swizzled
// global source (keeps ds_read_b128 at <=2-way bank conflict).
// EPI: 0 = f32 store; 1 = softplus(acc + bias[n]) f32; 2 = acc + res[idx] f32;
//      3 = bf16(acc); 4 = bf16(silu(auxb[idx]) * acc)
// ---------------------------------------------------------------------------
template <int EPI>
__global__ __launch_bounds__(256, 2) void gemm_bt(
    const unsigned short* __restrict__ A, const unsigned short* __restrict__ B,
    float* __restrict__ outf, unsigned short* __restrict__ outb,
    const float* __restrict__ auxf, const unsigned short* __restrict__ auxb,
    int N, int K) {
  __shared__ unsigned short As[128 * 64];
  __shared__ unsigned short Bs[128 * 64];
  const int tid = threadIdx.x;
  const int l = tid & 63;
  const int wid = tid >> 6;
  const int m0 = blockIdx.y * 128, n0 = blockIdx.x * 128;
  const int wr = wid >> 1, wc = wid & 1;

  f32x4 zero = {0.f, 0.f, 0.f, 0.f};
  f32x4 acc[4][4];
#pragma unroll
  for (int i = 0; i < 4; ++i)
#pragma unroll
    for (int j = 0; j < 4; ++j) acc[i][j] = zero;

  const int rlock = l >> 3;              // row within 8-row chunk
  const int clog = (l & 7) ^ rlock;      // logical 16B-chunk (swizzled source)

  for (int kt = 0; kt < K; kt += 64) {
#pragma unroll
    for (int j = 0; j < 4; ++j) {
      int chunk = wid * 4 + j;           // 0..15, 8 rows each
      int row = chunk * 8 + rlock;
      const unsigned short* ga = A + (size_t)(m0 + row) * K + kt + clog * 8;
      __builtin_amdgcn_global_load_lds(
          (const __attribute__((address_space(1))) void*)ga,
          (__attribute__((address_space(3))) void*)(As + chunk * 512), 16, 0, 0);
      const unsigned short* gb = B + (size_t)(n0 + row) * K + kt + clog * 8;
      __builtin_amdgcn_global_load_lds(
          (const __attribute__((address_space(1))) void*)gb,
          (__attribute__((address_space(3))) void*)(Bs + chunk * 512), 16, 0, 0);
    }
    asm volatile("s_waitcnt vmcnt(0)" ::: "memory");
    __syncthreads();

#pragma unroll
    for (int ks = 0; ks < 2; ++ks) {
      bf16x8 af[4], bfr[4];
#pragma unroll
      for (int mi = 0; mi < 4; ++mi) {
        int row = wr * 64 + mi * 16 + (l & 15);
        int c = ks * 4 + (l >> 4);
        int phys = c ^ (row & 7);
        af[mi] = *(const bf16x8*)&As[row * 64 + phys * 8];
      }
#pragma unroll
      for (int ni = 0; ni < 4; ++ni) {
        int row = wc * 64 + ni * 16 + (l & 15);
        int c = ks * 4 + (l >> 4);
        int phys = c ^ (row & 7);
        bfr[ni] = *(const bf16x8*)&Bs[row * 64 + phys * 8];
      }
#pragma unroll
      for (int mi = 0; mi < 4; ++mi)
#pragma unroll
        for (int ni = 0; ni < 4; ++ni)
          acc[mi][ni] = __builtin_amdgcn_mfma_f32_16x16x32_bf16(
              af[mi], bfr[ni], acc[mi][ni], 0, 0, 0);
    }
    __syncthreads();
  }

#pragma unroll
  for (int mi = 0; mi < 4; ++mi) {
#pragma unroll
    for (int ni = 0; ni < 4; ++ni) {
#pragma unroll
      for (int r = 0; r < 4; ++r) {
        int row = m0 + wr * 64 + mi * 16 + (l >> 4) * 4 + r;
        int col = n0 + wc * 64 + ni * 16 + (l & 15);
        size_t idx = (size_t)row * N + col;
        float v = acc[mi][ni][r];
        if constexpr (EPI == 0) {
          outf[idx] = v;
        } else if constexpr (EPI == 1) {
          float x = v + auxf[col];
          outf[idx] = (x > 15.f) ? x : __logf(1.f + __expf(x));
        } else if constexpr (EPI == 2) {
          outf[idx] = v + auxf[idx];
        } else if constexpr (EPI == 3) {
          outb[idx] = f2b(v);
        } else {  // EPI == 4
          float gv = b2f(auxb[idx]);
          float sg = gv / (1.f + __expf(-gv));
          outb[idx] = f2b(sg * v);
        }
      }
    }
  }
}

// ---------------------------------------------------------------------------
// Selective scan. One wave per (b, g, p-pair). lane = (p_half<<5) | n.
// h recurrence in fp32; fused D-skip + silu(z) gating; writes bf16 y_gated.
// zx layout per row (5248): z[0:2048] x[2048:2560] B[2560:3072] C[3072:5120]
// ---------------------------------------------------------------------------
__global__ __launch_bounds__(256) void scan_kernel(
    const float* __restrict__ zx, const float* __restrict__ dtb,
    const float* __restrict__ A_log, const float* __restrict__ D_param,
    unsigned short* __restrict__ ygated) {
  int lane = threadIdx.x & 63;
  int w = blockIdx.x * 4 + (threadIdx.x >> 6);  // 0..2047
  int b = w >> 10;
  int rem = w & 1023;
  int g = rem >> 4;
  int pp = rem & 15;
  int p = pp * 2 + (lane >> 5);
  int n = lane & 31;
  int gp = g * 32 + p;

  float Areg = -__expf(A_log[(size_t)gp * 32 + n]);
  float Dv = D_param[gp];

  const float* zrow = zx + (size_t)b * 1024 * 5248;
  const float* dtrow = dtb + (size_t)b * 1024 * 2048;
  unsigned short* yrow = ygated + (size_t)b * 1024 * 2048;
  const int xoff = 2048 + (g >> 2) * 32 + p;
  const int boff = 2560 + (g >> 2) * 32 + n;
  const int coff = 3072 + g * 32 + n;

  float h = 0.f;
  for (int t = 0; t < 1024; ++t) {
    const float* r = zrow + (size_t)t * 5248;
    float dtv = dtrow[t * 2048 + gp];
    float xv = r[xoff];
    float Bv = r[boff];
    float Cv = r[coff];
    float dA = __expf(dtv * Areg);
    h = fmaf(dA, h, dtv * xv * Bv);
    float yc = h * Cv;
    yc += __shfl_xor(yc, 1);
    yc += __shfl_xor(yc, 2);
    yc += __shfl_xor(yc, 4);
    yc += __shfl_xor(yc, 8);
    yc += __shfl_xor(yc, 16);
    if (n == 0) {
      float y = fmaf(xv, Dv, yc);
      float zv = r[gp];
      float sg = zv / (1.f + __expf(-zv));
      yrow[t * 2048 + gp] = f2b(y * sg);
    }
  }
}

// ---------------------------------------------------------------------------
// launch
// ---------------------------------------------------------------------------
extern "C" void kernel_launch(void* const* d_in, const int* in_sizes, int n_in,
                              void* d_out, int out_size, void* d_ws, size_t ws_size,
                              hipStream_t stream) {
  const float* hidden    = (const float*)d_in[0];
  const float* in_proj_w = (const float*)d_in[1];
  const float* dt_proj_w = (const float*)d_in[2];
  const float* dt_proj_b = (const float*)d_in[3];
  const float* A_log     = (const float*)d_in[4];
  const float* D_param   = (const float*)d_in[5];
  const float* out_proj_w= (const float*)d_in[6];
  const float* gate_w    = (const float*)d_in[7];
  const float* up_w      = (const float*)d_in[8];
  const float* down_w    = (const float*)d_in[9];
  const float* norm1_w   = (const float*)d_in[10];
  const float* norm2_w   = (const float*)d_in[11];
  float* out = (float*)d_out;
  char* ws = (char*)d_ws;

  // workspace layout (bytes); aliased regions noted
  const size_t o_w_in   = 0;                     // 5248*2048 bf16
  const size_t o_w_dt   = 21495808;              // 2048*128 bf16
  const size_t o_w_out  = 22020096;              // 2048*2048 bf16
  const size_t o_w_gate = 30408704;              // 5632*2048 bf16
  const size_t o_w_up   = 53477376;              // 5632*2048 bf16
  const size_t o_w_down = 76546048;              // 2048*5632 bf16
  const size_t o_u      = 99614720;              // 2048*2048 bf16 (alias: xn)
  const size_t o_zx     = 108003328;             // 2048*5248 f32  (alias: gate bf16)
  const size_t o_dtraw  = 150994944;             // 2048*128 bf16
  const size_t o_dtbuf  = 151519232;             // 2048*2048 f32  (alias: hsig bf16, spills into yg)
  const size_t o_yg     = 168296448;             // 2048*2048 bf16
  const size_t o_h      = 176685056;             // 2048*2048 f32
  // total = 193462272 bytes

  unsigned short* w_in   = (unsigned short*)(ws + o_w_in);
  unsigned short* w_dt   = (unsigned short*)(ws + o_w_dt);
  unsigned short* w_out  = (unsigned short*)(ws + o_w_out);
  unsigned short* w_gate = (unsigned short*)(ws + o_w_gate);
  unsigned short* w_up   = (unsigned short*)(ws + o_w_up);
  unsigned short* w_down = (unsigned short*)(ws + o_w_down);
  unsigned short* u_bf   = (unsigned short*)(ws + o_u);
  unsigned short* xn_bf  = (unsigned short*)(ws + o_u);      // alias (u dead)
  float*          zxb    = (float*)(ws + o_zx);
  unsigned short* gate_b = (unsigned short*)(ws + o_zx);     // alias (zx dead)
  unsigned short* dtraw  = (unsigned short*)(ws + o_dtraw);
  float*          dtbuf  = (float*)(ws + o_dtbuf);
  unsigned short* hsig   = (unsigned short*)(ws + o_dtbuf);  // alias (dtbuf+yg dead)
  unsigned short* yg     = (unsigned short*)(ws + o_yg);
  float*          hbuf   = (float*)(ws + o_h);

  auto cvt = [&](const float* src, unsigned short* dst, size_t n) {
    int n2 = (int)(n / 2);
    cvt_bf16<<<(n2 + 255) / 256, 256, 0, stream>>>((const float2*)src,
                                                   (unsigned int*)dst, n2);
  };

  // 1. weights -> bf16
  cvt(in_proj_w, w_in, (size_t)5248 * 2048);
  cvt(dt_proj_w, w_dt, (size_t)2048 * 128);
  cvt(out_proj_w, w_out, (size_t)2048 * 2048);
  cvt(gate_w, w_gate, (size_t)5632 * 2048);
  cvt(up_w, w_up, (size_t)5632 * 2048);
  cvt(down_w, w_down, (size_t)2048 * 5632);

  // 2. u = rmsnorm(hidden, norm1) -> bf16
  rmsnorm_cast<<<2048, 256, 0, stream>>>(hidden, norm1_w, u_bf);

  // 3. zxbcdt = u @ in_proj_w^T   [2048, 5248] f32
  gemm_bt<0><<<dim3(5248 / 128, 16), 256, 0, stream>>>(
      u_bf, w_in, zxb, nullptr, nullptr, nullptr, 5248, 2048);

  // 4. dt_raw slice -> bf16
  cast_dtraw<<<1024, 256, 0, stream>>>(zxb, dtraw);

  // 5. dt = softplus(dt_raw @ dt_proj_w^T + b)  [2048, 2048] f32
  gemm_bt<1><<<dim3(16, 16), 256, 0, stream>>>(
      dtraw, w_dt, dtbuf, nullptr, dt_proj_b, nullptr, 2048, 128);

  // 6. selective scan + D-skip + silu(z) gate -> yg bf16
  scan_kernel<<<512, 256, 0, stream>>>(zxb, dtbuf, A_log, D_param, yg);

  // 7. h = hidden + yg @ out_proj_w^T   [2048, 2048] f32
  gemm_bt<2><<<dim3(16, 16), 256, 0, stream>>>(
      yg, w_out, hbuf, nullptr, hidden, nullptr, 2048, 2048);

  // 8. xn = rmsnorm(h, norm2) -> bf16
  rmsnorm_cast<<<2048, 256, 0, stream>>>(hbuf, norm2_w, xn_bf);

  // 9. gate = xn @ gate_w^T -> bf16
  gemm_bt<3><<<dim3(5632 / 128, 16), 256, 0, stream>>>(
      xn_bf, w_gate, nullptr, gate_b, nullptr, nullptr, 5632, 2048);

  // 10. hsig = silu(gate) * (xn @ up_w^T) -> bf16
  gemm_bt<4><<<dim3(5632 / 128, 16), 256, 0, stream>>>(
      xn_bf, w_up, nullptr, hsig, nullptr, gate_b, 5632, 2048);

  // 11. out = h + hsig @ down_w^T
  gemm_bt<2><<<dim3(16, 16), 256, 0, stream>>>(
      hsig, w_down, out, nullptr, hbuf, nullptr, 2048, 5632);
}

// Round 3
// 852.114 us; speedup vs baseline: 1.6101x; 1.6101x over previous
//
#include <hip/hip_runtime.h>

// ---------------------------------------------------------------------------
// MambaDecoderLayer fused implementation for MI355X (gfx950)
// Shapes: B=2, L=1024 (rows=2048), D_MODEL=2048, D_INNER=2048, D_XB=512,
// D_STATE=32, DT_RANK=128, D_FF=5632, proj_dim=5248
// ---------------------------------------------------------------------------

typedef __attribute__((ext_vector_type(4))) float f32x4;
typedef __attribute__((ext_vector_type(8))) __bf16 bf16x8;

#define NC 16   // time chunks for the parallel scan
#define TC 64   // 1024 / NC

__device__ __forceinline__ unsigned short f2b(float f) {
  unsigned u = __builtin_bit_cast(unsigned, f);
  u += 0x7fffu + ((u >> 16) & 1u);          // round-to-nearest-even
  return (unsigned short)(u >> 16);
}
__device__ __forceinline__ float b2f(unsigned short b) {
  return __builtin_bit_cast(float, ((unsigned)b) << 16);
}

// ---------------------------------------------------------------------------
// fp32 -> bf16 bulk convert (pairs)
// ---------------------------------------------------------------------------
__global__ __launch_bounds__(256) void cvt_bf16(const float2* __restrict__ in,
                                                unsigned int* __restrict__ out,
                                                int n2) {
  int i = blockIdx.x * 256 + threadIdx.x;
  if (i >= n2) return;
  float2 v = in[i];
  out[i] = (unsigned)f2b(v.x) | ((unsigned)f2b(v.y) << 16);
}

// ---------------------------------------------------------------------------
// RMSNorm (rows of 2048) -> bf16 output
// ---------------------------------------------------------------------------
__global__ __launch_bounds__(256) void rmsnorm_cast(const float* __restrict__ x,
                                                    const float* __restrict__ w,
                                                    unsigned short* __restrict__ out) {
  int row = blockIdx.x;
  int t = threadIdx.x;
  const float* xr = x + (size_t)row * 2048;
  float4 v0 = *(const float4*)&xr[t * 8];
  float4 v1 = *(const float4*)&xr[t * 8 + 4];
  float s = v0.x * v0.x + v0.y * v0.y + v0.z * v0.z + v0.w * v0.w +
            v1.x * v1.x + v1.y * v1.y + v1.z * v1.z + v1.w * v1.w;
#pragma unroll
  for (int off = 1; off < 64; off <<= 1) s += __shfl_xor(s, off);
  __shared__ float red[4];
  if ((t & 63) == 0) red[t >> 6] = s;
  __syncthreads();
  s = red[0] + red[1] + red[2] + red[3];
  float scale = rsqrtf(s * (1.0f / 2048.0f) + 1e-5f);
  float4 w0 = *(const float4*)&w[t * 8];
  float4 w1 = *(const float4*)&w[t * 8 + 4];
  uint4 o;
  o.x = (unsigned)f2b(v0.x * scale * w0.x) | ((unsigned)f2b(v0.y * scale * w0.y) << 16);
  o.y = (unsigned)f2b(v0.z * scale * w0.z) | ((unsigned)f2b(v0.w * scale * w0.w) << 16);
  o.z = (unsigned)f2b(v1.x * scale * w1.x) | ((unsigned)f2b(v1.y * scale * w1.y) << 16);
  o.w = (unsigned)f2b(v1.z * scale * w1.z) | ((unsigned)f2b(v1.w * scale * w1.w) << 16);
  *(uint4*)&out[(size_t)row * 2048 + t * 8] = o;
}

// ---------------------------------------------------------------------------
// Extract dt_raw slice of zxbcdt (cols 5120..5248) -> bf16 [2048,128]
// ---------------------------------------------------------------------------
__global__ __launch_bounds__(256) void cast_dtraw(const float* __restrict__ zx,
                                                  unsigned short* __restrict__ dst) {
  int i = blockIdx.x * 256 + threadIdx.x;  // 0..262143
  int r = i >> 7, c = i & 127;
  dst[i] = f2b(zx[(size_t)r * 5248 + 5120 + c]);
}

// ---------------------------------------------------------------------------
// bf16 MFMA GEMM, out[m,n] = sum_k A[m,k] * W[n,k]  (W row-major [N,K])
// 128x128 tile, BK=64, 4 waves (2x2), global_load_lds staging with XOR-swizzled
// global source (keeps ds_read_b128 at <=2-way bank conflict).
// EPI: 0 = f32 store; 1 = softplus(acc + bias[n]) f32; 2 = acc + res[idx] f32;
//      3 = bf16(acc); 4 = bf16(silu(auxb[idx]) * acc)
// ---------------------------------------------------------------------------
template <int EPI>
__global__ __launch_bounds__(256, 2) void gemm_bt(
    const unsigned short* __restrict__ A, const unsigned short* __restrict__ B,
    float* __restrict__ outf, unsigned short* __restrict__ outb,
    const float* __restrict__ auxf, const unsigned short* __restrict__ auxb,
    int N, int K) {
  __shared__ unsigned short As[128 * 64];
  __shared__ unsigned short Bs[128 * 64];
  const int tid = threadIdx.x;
  const int l = tid & 63;
  const int wid = tid >> 6;
  const int m0 = blockIdx.y * 128, n0 = blockIdx.x * 128;
  const int wr = wid >> 1, wc = wid & 1;

  f32x4 zero = {0.f, 0.f, 0.f, 0.f};
  f32x4 acc[4][4];
#pragma unroll
  for (int i = 0; i < 4; ++i)
#pragma unroll
    for (int j = 0; j < 4; ++j) acc[i][j] = zero;

  const int rlock = l >> 3;              // row within 8-row chunk
  const int clog = (l & 7) ^ rlock;      // logical 16B-chunk (swizzled source)

  for (int kt = 0; kt < K; kt += 64) {
#pragma unroll
    for (int j = 0; j < 4; ++j) {
      int chunk = wid * 4 + j;           // 0..15, 8 rows each
      int row = chunk * 8 + rlock;
      const unsigned short* ga = A + (size_t)(m0 + row) * K + kt + clog * 8;
      __builtin_amdgcn_global_load_lds(
          (const __attribute__((address_space(1))) void*)ga,
          (__attribute__((address_space(3))) void*)(As + chunk * 512), 16, 0, 0);
      const unsigned short* gb = B + (size_t)(n0 + row) * K + kt + clog * 8;
      __builtin_amdgcn_global_load_lds(
          (const __attribute__((address_space(1))) void*)gb,
          (__attribute__((address_space(3))) void*)(Bs + chunk * 512), 16, 0, 0);
    }
    asm volatile("s_waitcnt vmcnt(0)" ::: "memory");
    __syncthreads();

#pragma unroll
    for (int ks = 0; ks < 2; ++ks) {
      bf16x8 af[4], bfr[4];
#pragma unroll
      for (int mi = 0; mi < 4; ++mi) {
        int row = wr * 64 + mi * 16 + (l & 15);
        int c = ks * 4 + (l >> 4);
        int phys = c ^ (row & 7);
        af[mi] = *(const bf16x8*)&As[row * 64 + phys * 8];
      }
#pragma unroll
      for (int ni = 0; ni < 4; ++ni) {
        int row = wc * 64 + ni * 16 + (l & 15);
        int c = ks * 4 + (l >> 4);
        int phys = c ^ (row & 7);
        bfr[ni] = *(const bf16x8*)&Bs[row * 64 + phys * 8];
      }
#pragma unroll
      for (int mi = 0; mi < 4; ++mi)
#pragma unroll
        for (int ni = 0; ni < 4; ++ni)
          acc[mi][ni] = __builtin_amdgcn_mfma_f32_16x16x32_bf16(
              af[mi], bfr[ni], acc[mi][ni], 0, 0, 0);
    }
    __syncthreads();
  }

#pragma unroll
  for (int mi = 0; mi < 4; ++mi) {
#pragma unroll
    for (int ni = 0; ni < 4; ++ni) {
#pragma unroll
      for (int r = 0; r < 4; ++r) {
        int row = m0 + wr * 64 + mi * 16 + (l >> 4) * 4 + r;
        int col = n0 + wc * 64 + ni * 16 + (l & 15);
        size_t idx = (size_t)row * N + col;
        float v = acc[mi][ni][r];
        if constexpr (EPI == 0) {
          outf[idx] = v;
        } else if constexpr (EPI == 1) {
          float x = v + auxf[col];
          outf[idx] = (x > 15.f) ? x : __logf(1.f + __expf(x));
        } else if constexpr (EPI == 2) {
          outf[idx] = v + auxf[idx];
        } else if constexpr (EPI == 3) {
          outb[idx] = f2b(v);
        } else {  // EPI == 4
          float gv = b2f(auxb[idx]);
          float sg = gv / (1.f + __expf(-gv));
          outb[idx] = f2b(sg * v);
        }
      }
    }
  }
}

// ---------------------------------------------------------------------------
// Chunked parallel selective scan.
// The per-element recurrence h[e]_t = dA_t[e]*h[e]_{t-1} + b_t[e] is linear,
// so: pass 1 computes each chunk's local scan (h0=0) + cumulative dA product;
// pass 2 serially combines the 16 chunk summaries into true chunk-start
// states H0; pass 3 re-runs each chunk from its H0 with the fused epilogue.
// Wave mapping (passes 1/3): wave w -> (b, g, p-pair, chunk);
// lane = (p_half<<5) | n.  elem id = wv*64 + lane (contiguous per wave).
// zx layout per row (5248): z[0:2048] x[2048:2560] B[2560:3072] C[3072:5120]
// ---------------------------------------------------------------------------
__global__ __launch_bounds__(256) void scan_partial(
    const float* __restrict__ zx, const float* __restrict__ dtb,
    const float* __restrict__ A_log,
    float* __restrict__ hpart, float* __restrict__ aprod) {
  int lane = threadIdx.x & 63;
  int w = blockIdx.x * 4 + (threadIdx.x >> 6);  // 0..32767
  int chunk = w & (NC - 1);
  int wv = w >> 4;              // 0..2047
  int b = wv >> 10;
  int rem = wv & 1023;
  int g = rem >> 4;
  int pp = rem & 15;
  int p = pp * 2 + (lane >> 5);
  int n = lane & 31;
  int gp = g * 32 + p;

  float Areg = -__expf(A_log[(size_t)gp * 32 + n]);

  const float* zrow = zx + (size_t)b * 1024 * 5248;
  const float* dtrow = dtb + (size_t)b * 1024 * 2048;
  const int xoff = 2048 + (g >> 2) * 32 + p;
  const int boff = 2560 + (g >> 2) * 32 + n;

  float h = 0.f, ap = 1.f;
  const int t0 = chunk * TC;
#pragma unroll 4
  for (int t = t0; t < t0 + TC; ++t) {
    const float* r = zrow + (size_t)t * 5248;
    float dtv = dtrow[t * 2048 + gp];
    float xv = r[xoff];
    float Bv = r[boff];
    float dA = __expf(dtv * Areg);
    h = fmaf(dA, h, dtv * xv * Bv);
    ap *= dA;
  }
  hpart[(size_t)chunk * 131072 + wv * 64 + lane] = h;
  aprod[(size_t)chunk * 131072 + wv * 64 + lane] = ap;
}

__global__ __launch_bounds__(256) void scan_combine(
    const float* __restrict__ hpart, const float* __restrict__ aprod,
    float* __restrict__ H0) {
  int e = blockIdx.x * 256 + threadIdx.x;  // 0..131071
  float H = 0.f;
#pragma unroll
  for (int c = 0; c < NC; ++c) {
    H0[(size_t)c * 131072 + e] = H;
    H = fmaf(aprod[(size_t)c * 131072 + e], H, hpart[(size_t)c * 131072 + e]);
  }
}

__global__ __launch_bounds__(256) void scan_final(
    const float* __restrict__ zx, const float* __restrict__ dtb,
    const float* __restrict__ A_log, const float* __restrict__ D_param,
    const float* __restrict__ H0, unsigned short* __restrict__ ygated) {
  int lane = threadIdx.x & 63;
  int w = blockIdx.x * 4 + (threadIdx.x >> 6);  // 0..32767
  int chunk = w & (NC - 1);
  int wv = w >> 4;              // 0..2047
  int b = wv >> 10;
  int rem = wv & 1023;
  int g = rem >> 4;
  int pp = rem & 15;
  int p = pp * 2 + (lane >> 5);
  int n = lane & 31;
  int gp = g * 32 + p;

  float Areg = -__expf(A_log[(size_t)gp * 32 + n]);
  float Dv = D_param[gp];

  const float* zrow = zx + (size_t)b * 1024 * 5248;
  const float* dtrow = dtb + (size_t)b * 1024 * 2048;
  unsigned short* yrow = ygated + (size_t)b * 1024 * 2048;
  const int xoff = 2048 + (g >> 2) * 32 + p;
  const int boff = 2560 + (g >> 2) * 32 + n;
  const int coff = 3072 + g * 32 + n;

  float h = H0[(size_t)chunk * 131072 + wv * 64 + lane];
  const int t0 = chunk * TC;
#pragma unroll 2
  for (int t = t0; t < t0 + TC; ++t) {
    const float* r = zrow + (size_t)t * 5248;
    float dtv = dtrow[t * 2048 + gp];
    float xv = r[xoff];
    float Bv = r[boff];
    float Cv = r[coff];
    float dA = __expf(dtv * Areg);
    h = fmaf(dA, h, dtv * xv * Bv);
    float yc = h * Cv;
    yc += __shfl_xor(yc, 1);
    yc += __shfl_xor(yc, 2);
    yc += __shfl_xor(yc, 4);
    yc += __shfl_xor(yc, 8);
    yc += __shfl_xor(yc, 16);
    if (n == 0) {
      float y = fmaf(xv, Dv, yc);
      float zv = r[gp];
      float sg = zv / (1.f + __expf(-zv));
      yrow[t * 2048 + gp] = f2b(y * sg);
    }
  }
}

// ---------------------------------------------------------------------------
// launch
// ---------------------------------------------------------------------------
extern "C" void kernel_launch(void* const* d_in, const int* in_sizes, int n_in,
                              void* d_out, int out_size, void* d_ws, size_t ws_size,
                              hipStream_t stream) {
  const float* hidden    = (const float*)d_in[0];
  const float* in_proj_w = (const float*)d_in[1];
  const float* dt_proj_w = (const float*)d_in[2];
  const float* dt_proj_b = (const float*)d_in[3];
  const float* A_log     = (const float*)d_in[4];
  const float* D_param   = (const float*)d_in[5];
  const float* out_proj_w= (const float*)d_in[6];
  const float* gate_w    = (const float*)d_in[7];
  const float* up_w      = (const float*)d_in[8];
  const float* down_w    = (const float*)d_in[9];
  const float* norm1_w   = (const float*)d_in[10];
  const float* norm2_w   = (const float*)d_in[11];
  float* out = (float*)d_out;
  char* ws = (char*)d_ws;

  // workspace layout (bytes); aliased regions noted
  const size_t o_w_in   = 0;                     // 5248*2048 bf16
  const size_t o_w_dt   = 21495808;              // 2048*128 bf16
  const size_t o_w_out  = 22020096;              // 2048*2048 bf16
  const size_t o_w_gate = 30408704;              // 5632*2048 bf16
  const size_t o_w_up   = 53477376;              // 5632*2048 bf16
  const size_t o_w_down = 76546048;              // 2048*5632 bf16
  const size_t o_u      = 99614720;              // 2048*2048 bf16 (alias: xn, scan H0)
  const size_t o_zx     = 108003328;             // 2048*5248 f32  (alias: gate bf16)
  const size_t o_dtraw  = 150994944;             // 2048*128 bf16
  const size_t o_dtbuf  = 151519232;             // 2048*2048 f32  (alias: hsig bf16, spills into yg)
  const size_t o_yg     = 168296448;             // 2048*2048 bf16
  const size_t o_h      = 176685056;             // 2048*2048 f32  (alias: scan hpart+aprod)
  // total = 193462272 bytes

  unsigned short* w_in   = (unsigned short*)(ws + o_w_in);
  unsigned short* w_dt   = (unsigned short*)(ws + o_w_dt);
  unsigned short* w_out  = (unsigned short*)(ws + o_w_out);
  unsigned short* w_gate = (unsigned short*)(ws + o_w_gate);
  unsigned short* w_up   = (unsigned short*)(ws + o_w_up);
  unsigned short* w_down = (unsigned short*)(ws + o_w_down);
  unsigned short* u_bf   = (unsigned short*)(ws + o_u);
  unsigned short* xn_bf  = (unsigned short*)(ws + o_u);      // alias (u dead)
  float*          zxb    = (float*)(ws + o_zx);
  unsigned short* gate_b = (unsigned short*)(ws + o_zx);     // alias (zx dead)
  unsigned short* dtraw  = (unsigned short*)(ws + o_dtraw);
  float*          dtbuf  = (float*)(ws + o_dtbuf);
  unsigned short* hsig   = (unsigned short*)(ws + o_dtbuf);  // alias (dtbuf+yg dead)
  unsigned short* yg     = (unsigned short*)(ws + o_yg);
  float*          hbuf   = (float*)(ws + o_h);
  // scan scratch: hpart+aprod (8.39 MB each) exactly fill hbuf's 16.78 MB
  // region (hbuf written only at step 7, after the scan). H0 (8.39 MB)
  // exactly fills u_bf's region (u dead after step 3; xn written step 8).
  float* hpart = (float*)(ws + o_h);
  float* aprod = (float*)(ws + o_h + 8388608);
  float* H0buf = (float*)(ws + o_u);

  auto cvt = [&](const float* src, unsigned short* dst, size_t n) {
    int n2 = (int)(n / 2);
    cvt_bf16<<<(n2 + 255) / 256, 256, 0, stream>>>((const float2*)src,
                                                   (unsigned int*)dst, n2);
  };

  // 1. weights -> bf16
  cvt(in_proj_w, w_in, (size_t)5248 * 2048);
  cvt(dt_proj_w, w_dt, (size_t)2048 * 128);
  cvt(out_proj_w, w_out, (size_t)2048 * 2048);
  cvt(gate_w, w_gate, (size_t)5632 * 2048);
  cvt(up_w, w_up, (size_t)5632 * 2048);
  cvt(down_w, w_down, (size_t)2048 * 5632);

  // 2. u = rmsnorm(hidden, norm1) -> bf16
  rmsnorm_cast<<<2048, 256, 0, stream>>>(hidden, norm1_w, u_bf);

  // 3. zxbcdt = u @ in_proj_w^T   [2048, 5248] f32
  gemm_bt<0><<<dim3(5248 / 128, 16), 256, 0, stream>>>(
      u_bf, w_in, zxb, nullptr, nullptr, nullptr, 5248, 2048);

  // 4. dt_raw slice -> bf16
  cast_dtraw<<<1024, 256, 0, stream>>>(zxb, dtraw);

  // 5. dt = softplus(dt_raw @ dt_proj_w^T + b)  [2048, 2048] f32
  gemm_bt<1><<<dim3(16, 16), 256, 0, stream>>>(
      dtraw, w_dt, dtbuf, nullptr, dt_proj_b, nullptr, 2048, 128);

  // 6. chunked selective scan + D-skip + silu(z) gate -> yg bf16
  scan_partial<<<8192, 256, 0, stream>>>(zxb, dtbuf, A_log, hpart, aprod);
  scan_combine<<<512, 256, 0, stream>>>(hpart, aprod, H0buf);
  scan_final<<<8192, 256, 0, stream>>>(zxb, dtbuf, A_log, D_param, H0buf, yg);

  // 7. h = hidden + yg @ out_proj_w^T   [2048, 2048] f32
  gemm_bt<2><<<dim3(16, 16), 256, 0, stream>>>(
      yg, w_out, hbuf, nullptr, hidden, nullptr, 2048, 2048);

  // 8. xn = rmsnorm(h, norm2) -> bf16
  rmsnorm_cast<<<2048, 256, 0, stream>>>(hbuf, norm2_w, xn_bf);

  // 9. gate = xn @ gate_w^T -> bf16
  gemm_bt<3><<<dim3(5632 / 128, 16), 256, 0, stream>>>(
      xn_bf, w_gate, nullptr, gate_b, nullptr, nullptr, 5632, 2048);

  // 10. hsig = silu(gate) * (xn @ up_w^T) -> bf16
  gemm_bt<4><<<dim3(5632 / 128, 16), 256, 0, stream>>>(
      xn_bf, w_up, nullptr, hsig, nullptr, gate_b, 5632, 2048);

  // 11. out = h + hsig @ down_w^T
  gemm_bt<2><<<dim3(16, 16), 256, 0, stream>>>(
      hsig, w_down, out, nullptr, hbuf, nullptr, 2048, 5632);
}

// Round 4
// 668.243 us; speedup vs baseline: 2.0532x; 1.2752x over previous
//
#include <hip/hip_runtime.h>

// ---------------------------------------------------------------------------
// MambaDecoderLayer fused implementation for MI355X (gfx950)
// Shapes: B=2, L=1024 (rows=2048), D_MODEL=2048, D_INNER=2048, D_XB=512,
// D_STATE=32, DT_RANK=128, D_FF=5632, proj_dim=5248
// ---------------------------------------------------------------------------

typedef __attribute__((ext_vector_type(4))) float f32x4;
typedef __attribute__((ext_vector_type(8))) __bf16 bf16x8;

#define NC 16   // time chunks for the parallel scan
#define TC 64   // 1024 / NC

__device__ __forceinline__ unsigned short f2b(float f) {
  unsigned u = __builtin_bit_cast(unsigned, f);
  u += 0x7fffu + ((u >> 16) & 1u);          // round-to-nearest-even
  return (unsigned short)(u >> 16);
}
__device__ __forceinline__ float b2f(unsigned short b) {
  return __builtin_bit_cast(float, ((unsigned)b) << 16);
}

// ---------------------------------------------------------------------------
// fp32 -> bf16 bulk convert (pairs)
// ---------------------------------------------------------------------------
__global__ __launch_bounds__(256) void cvt_bf16(const float2* __restrict__ in,
                                                unsigned int* __restrict__ out,
                                                int n2) {
  int i = blockIdx.x * 256 + threadIdx.x;
  if (i >= n2) return;
  float2 v = in[i];
  out[i] = (unsigned)f2b(v.x) | ((unsigned)f2b(v.y) << 16);
}

// ---------------------------------------------------------------------------
// RMSNorm (rows of 2048) -> bf16 output
// ---------------------------------------------------------------------------
__global__ __launch_bounds__(256) void rmsnorm_cast(const float* __restrict__ x,
                                                    const float* __restrict__ w,
                                                    unsigned short* __restrict__ out) {
  int row = blockIdx.x;
  int t = threadIdx.x;
  const float* xr = x + (size_t)row * 2048;
  float4 v0 = *(const float4*)&xr[t * 8];
  float4 v1 = *(const float4*)&xr[t * 8 + 4];
  float s = v0.x * v0.x + v0.y * v0.y + v0.z * v0.z + v0.w * v0.w +
            v1.x * v1.x + v1.y * v1.y + v1.z * v1.z + v1.w * v1.w;
#pragma unroll
  for (int off = 1; off < 64; off <<= 1) s += __shfl_xor(s, off);
  __shared__ float red[4];
  if ((t & 63) == 0) red[t >> 6] = s;
  __syncthreads();
  s = red[0] + red[1] + red[2] + red[3];
  float scale = rsqrtf(s * (1.0f / 2048.0f) + 1e-5f);
  float4 w0 = *(const float4*)&w[t * 8];
  float4 w1 = *(const float4*)&w[t * 8 + 4];
  uint4 o;
  o.x = (unsigned)f2b(v0.x * scale * w0.x) | ((unsigned)f2b(v0.y * scale * w0.y) << 16);
  o.y = (unsigned)f2b(v0.z * scale * w0.z) | ((unsigned)f2b(v0.w * scale * w0.w) << 16);
  o.z = (unsigned)f2b(v1.x * scale * w1.x) | ((unsigned)f2b(v1.y * scale * w1.y) << 16);
  o.w = (unsigned)f2b(v1.z * scale * w1.z) | ((unsigned)f2b(v1.w * scale * w1.w) << 16);
  *(uint4*)&out[(size_t)row * 2048 + t * 8] = o;
}

// ---------------------------------------------------------------------------
// Extract dt_raw slice of zxbcdt (cols 5120..5248) -> bf16 [2048,128]
// ---------------------------------------------------------------------------
__global__ __launch_bounds__(256) void cast_dtraw(const float* __restrict__ zx,
                                                  unsigned short* __restrict__ dst) {
  int i = blockIdx.x * 256 + threadIdx.x;  // 0..262143
  int r = i >> 7, c = i & 127;
  dst[i] = f2b(zx[(size_t)r * 5248 + 5120 + c]);
}

// ---------------------------------------------------------------------------
// bf16 MFMA GEMM, out[m,n] = sum_k A[m,k] * W[n,k]  (W row-major [N,K])
// 128x128 tile, BK=64, 4 waves (2x2), global_load_lds staging with XOR-swizzled
// global source (keeps ds_read_b128 at <=2-way bank conflict).
// EPI: 0 = f32 store; 1 = softplus(acc + bias[n]) f32; 2 = acc + res[idx] f32;
//      3 = bf16(acc); 4 = bf16(silu(auxb[idx]) * acc)
// ---------------------------------------------------------------------------
template <int EPI>
__global__ __launch_bounds__(256, 2) void gemm_bt(
    const unsigned short* __restrict__ A, const unsigned short* __restrict__ B,
    float* __restrict__ outf, unsigned short* __restrict__ outb,
    const float* __restrict__ auxf, const unsigned short* __restrict__ auxb,
    int N, int K) {
  __shared__ unsigned short As[128 * 64];
  __shared__ unsigned short Bs[128 * 64];
  const int tid = threadIdx.x;
  const int l = tid & 63;
  const int wid = tid >> 6;
  const int m0 = blockIdx.y * 128, n0 = blockIdx.x * 128;
  const int wr = wid >> 1, wc = wid & 1;

  f32x4 zero = {0.f, 0.f, 0.f, 0.f};
  f32x4 acc[4][4];
#pragma unroll
  for (int i = 0; i < 4; ++i)
#pragma unroll
    for (int j = 0; j < 4; ++j) acc[i][j] = zero;

  const int rlock = l >> 3;              // row within 8-row chunk
  const int clog = (l & 7) ^ rlock;      // logical 16B-chunk (swizzled source)

  for (int kt = 0; kt < K; kt += 64) {
#pragma unroll
    for (int j = 0; j < 4; ++j) {
      int chunk = wid * 4 + j;           // 0..15, 8 rows each
      int row = chunk * 8 + rlock;
      const unsigned short* ga = A + (size_t)(m0 + row) * K + kt + clog * 8;
      __builtin_amdgcn_global_load_lds(
          (const __attribute__((address_space(1))) void*)ga,
          (__attribute__((address_space(3))) void*)(As + chunk * 512), 16, 0, 0);
      const unsigned short* gb = B + (size_t)(n0 + row) * K + kt + clog * 8;
      __builtin_amdgcn_global_load_lds(
          (const __attribute__((address_space(1))) void*)gb,
          (__attribute__((address_space(3))) void*)(Bs + chunk * 512), 16, 0, 0);
    }
    asm volatile("s_waitcnt vmcnt(0)" ::: "memory");
    __syncthreads();

#pragma unroll
    for (int ks = 0; ks < 2; ++ks) {
      bf16x8 af[4], bfr[4];
#pragma unroll
      for (int mi = 0; mi < 4; ++mi) {
        int row = wr * 64 + mi * 16 + (l & 15);
        int c = ks * 4 + (l >> 4);
        int phys = c ^ (row & 7);
        af[mi] = *(const bf16x8*)&As[row * 64 + phys * 8];
      }
#pragma unroll
      for (int ni = 0; ni < 4; ++ni) {
        int row = wc * 64 + ni * 16 + (l & 15);
        int c = ks * 4 + (l >> 4);
        int phys = c ^ (row & 7);
        bfr[ni] = *(const bf16x8*)&Bs[row * 64 + phys * 8];
      }
#pragma unroll
      for (int mi = 0; mi < 4; ++mi)
#pragma unroll
        for (int ni = 0; ni < 4; ++ni)
          acc[mi][ni] = __builtin_amdgcn_mfma_f32_16x16x32_bf16(
              af[mi], bfr[ni], acc[mi][ni], 0, 0, 0);
    }
    __syncthreads();
  }

#pragma unroll
  for (int mi = 0; mi < 4; ++mi) {
#pragma unroll
    for (int ni = 0; ni < 4; ++ni) {
#pragma unroll
      for (int r = 0; r < 4; ++r) {
        int row = m0 + wr * 64 + mi * 16 + (l >> 4) * 4 + r;
        int col = n0 + wc * 64 + ni * 16 + (l & 15);
        size_t idx = (size_t)row * N + col;
        float v = acc[mi][ni][r];
        if constexpr (EPI == 0) {
          outf[idx] = v;
        } else if constexpr (EPI == 1) {
          float x = v + auxf[col];
          outf[idx] = (x > 15.f) ? x : __logf(1.f + __expf(x));
        } else if constexpr (EPI == 2) {
          outf[idx] = v + auxf[idx];
        } else if constexpr (EPI == 3) {
          outb[idx] = f2b(v);
        } else {  // EPI == 4
          float gv = b2f(auxb[idx]);
          float sg = gv / (1.f + __expf(-gv));
          outb[idx] = f2b(sg * v);
        }
      }
    }
  }
}

// ---------------------------------------------------------------------------
// Chunked parallel selective scan, 8 states per lane.
// wave <- (b, g, p-half, chunk); lane = p_loc*4 + ngrp owns p = ph*16+p_loc
// and n = ngrp*8 .. ngrp*8+7 (8 h-states in registers).
// Scratch layout: e = b*65536 + gp*32 + n (same as previous rounds).
// Pass 1 telescopes the dA product: prod exp(dt*A) = exp(A * sum dt).
// zx layout per row (5248): z[0:2048] x[2048:2560] B[2560:3072] C[3072:5120]
// ---------------------------------------------------------------------------
__global__ __launch_bounds__(256) void scan_partial(
    const float* __restrict__ zx, const float* __restrict__ dtb,
    const float* __restrict__ A_log,
    float* __restrict__ hpart, float* __restrict__ aprod) {
  int lane = threadIdx.x & 63;
  int w = blockIdx.x * 4 + (threadIdx.x >> 6);  // 0..4095
  int chunk = w & (NC - 1);
  int gh = w >> 4;              // 0..255
  int b = gh >> 7;
  int rem = gh & 127;
  int g = rem >> 1;
  int ph = rem & 1;
  int p_loc = lane >> 2;
  int ngrp = lane & 3;
  int p = ph * 16 + p_loc;
  int n0 = ngrp * 8;
  int gp = g * 32 + p;

  float4 a0 = *(const float4*)&A_log[(size_t)gp * 32 + n0];
  float4 a1 = *(const float4*)&A_log[(size_t)gp * 32 + n0 + 4];
  float Ar[8] = {-__expf(a0.x), -__expf(a0.y), -__expf(a0.z), -__expf(a0.w),
                 -__expf(a1.x), -__expf(a1.y), -__expf(a1.z), -__expf(a1.w)};

  const float* prow = zx + (size_t)(b * 1024 + chunk * TC) * 5248;
  const float* pdt = dtb + (size_t)(b * 1024 + chunk * TC) * 2048 + gp;
  const int xoff = 2048 + (g >> 2) * 32 + p;
  const int boff = 2560 + (g >> 2) * 32 + n0;

  float h[8];
#pragma unroll
  for (int j = 0; j < 8; ++j) h[j] = 0.f;
  float S = 0.f;

#pragma unroll 2
  for (int t = 0; t < TC; ++t) {
    float dtv = *pdt;
    float xv = prow[xoff];
    float4 B0 = *(const float4*)&prow[boff];
    float4 B1 = *(const float4*)&prow[boff + 4];
    float dtx = dtv * xv;
    S += dtv;
    float Bv[8] = {B0.x, B0.y, B0.z, B0.w, B1.x, B1.y, B1.z, B1.w};
#pragma unroll
    for (int j = 0; j < 8; ++j) {
      float dA = __expf(dtv * Ar[j]);
      h[j] = fmaf(dA, h[j], dtx * Bv[j]);
    }
    prow += 5248;
    pdt += 2048;
  }

  size_t e0 = (size_t)chunk * 131072 + (size_t)b * 65536 + (size_t)gp * 32 + n0;
  float4 h0 = {h[0], h[1], h[2], h[3]};
  float4 h1 = {h[4], h[5], h[6], h[7]};
  *(float4*)&hpart[e0] = h0;
  *(float4*)&hpart[e0 + 4] = h1;
  float4 p0 = {__expf(Ar[0] * S), __expf(Ar[1] * S), __expf(Ar[2] * S), __expf(Ar[3] * S)};
  float4 p1 = {__expf(Ar[4] * S), __expf(Ar[5] * S), __expf(Ar[6] * S), __expf(Ar[7] * S)};
  *(float4*)&aprod[e0] = p0;
  *(float4*)&aprod[e0 + 4] = p1;
}

__global__ __launch_bounds__(256) void scan_combine(
    const float* __restrict__ hpart, const float* __restrict__ aprod,
    float* __restrict__ H0) {
  int e = blockIdx.x * 256 + threadIdx.x;  // 0..131071
  float H = 0.f;
#pragma unroll
  for (int c = 0; c < NC; ++c) {
    H0[(size_t)c * 131072 + e] = H;
    H = fmaf(aprod[(size_t)c * 131072 + e], H, hpart[(size_t)c * 131072 + e]);
  }
}

__global__ __launch_bounds__(256) void scan_final(
    const float* __restrict__ zx, const float* __restrict__ dtb,
    const float* __restrict__ A_log, const float* __restrict__ D_param,
    const float* __restrict__ H0, unsigned short* __restrict__ ygated) {
  int lane = threadIdx.x & 63;
  int w = blockIdx.x * 4 + (threadIdx.x >> 6);  // 0..4095
  int chunk = w & (NC - 1);
  int gh = w >> 4;              // 0..255
  int b = gh >> 7;
  int rem = gh & 127;
  int g = rem >> 1;
  int ph = rem & 1;
  int p_loc = lane >> 2;
  int ngrp = lane & 3;
  int p = ph * 16 + p_loc;
  int n0 = ngrp * 8;
  int gp = g * 32 + p;

  float4 a0 = *(const float4*)&A_log[(size_t)gp * 32 + n0];
  float4 a1 = *(const float4*)&A_log[(size_t)gp * 32 + n0 + 4];
  float Ar[8] = {-__expf(a0.x), -__expf(a0.y), -__expf(a0.z), -__expf(a0.w),
                 -__expf(a1.x), -__expf(a1.y), -__expf(a1.z), -__expf(a1.w)};
  float Dv = D_param[gp];

  const float* prow = zx + (size_t)(b * 1024 + chunk * TC) * 5248;
  const float* pdt = dtb + (size_t)(b * 1024 + chunk * TC) * 2048 + gp;
  unsigned short* py = ygated + (size_t)(b * 1024 + chunk * TC) * 2048 + gp;
  const int xoff = 2048 + (g >> 2) * 32 + p;
  const int boff = 2560 + (g >> 2) * 32 + n0;
  const int coff = 3072 + g * 32 + n0;

  size_t e0 = (size_t)chunk * 131072 + (size_t)b * 65536 + (size_t)gp * 32 + n0;
  float4 h04 = *(const float4*)&H0[e0];
  float4 h14 = *(const float4*)&H0[e0 + 4];
  float h[8] = {h04.x, h04.y, h04.z, h04.w, h14.x, h14.y, h14.z, h14.w};

#pragma unroll 2
  for (int t = 0; t < TC; ++t) {
    float dtv = *pdt;
    float xv = prow[xoff];
    float4 B0 = *(const float4*)&prow[boff];
    float4 B1 = *(const float4*)&prow[boff + 4];
    float4 C0 = *(const float4*)&prow[coff];
    float4 C1 = *(const float4*)&prow[coff + 4];
    float dtx = dtv * xv;
    float Bv[8] = {B0.x, B0.y, B0.z, B0.w, B1.x, B1.y, B1.z, B1.w};
    float Cv[8] = {C0.x, C0.y, C0.z, C0.w, C1.x, C1.y, C1.z, C1.w};
    float y0 = 0.f, y1 = 0.f;
#pragma unroll
    for (int j = 0; j < 8; ++j) {
      float dA = __expf(dtv * Ar[j]);
      h[j] = fmaf(dA, h[j], dtx * Bv[j]);
      if (j & 1) y1 = fmaf(h[j], Cv[j], y1);
      else       y0 = fmaf(h[j], Cv[j], y0);
    }
    float yc = y0 + y1;
    yc += __shfl_xor(yc, 1);
    yc += __shfl_xor(yc, 2);
    if (ngrp == 0) {
      float y = fmaf(xv, Dv, yc);
      float zv = prow[gp];
      float sg = zv / (1.f + __expf(-zv));
      *py = f2b(y * sg);
    }
    prow += 5248;
    pdt += 2048;
    py += 2048;
  }
}

// ---------------------------------------------------------------------------
// launch
// ---------------------------------------------------------------------------
extern "C" void kernel_launch(void* const* d_in, const int* in_sizes, int n_in,
                              void* d_out, int out_size, void* d_ws, size_t ws_size,
                              hipStream_t stream) {
  const float* hidden    = (const float*)d_in[0];
  const float* in_proj_w = (const float*)d_in[1];
  const float* dt_proj_w = (const float*)d_in[2];
  const float* dt_proj_b = (const float*)d_in[3];
  const float* A_log     = (const float*)d_in[4];
  const float* D_param   = (const float*)d_in[5];
  const float* out_proj_w= (const float*)d_in[6];
  const float* gate_w    = (const float*)d_in[7];
  const float* up_w      = (const float*)d_in[8];
  const float* down_w    = (const float*)d_in[9];
  const float* norm1_w   = (const float*)d_in[10];
  const float* norm2_w   = (const float*)d_in[11];
  float* out = (float*)d_out;
  char* ws = (char*)d_ws;

  // workspace layout (bytes); aliased regions noted
  const size_t o_w_in   = 0;                     // 5248*2048 bf16
  const size_t o_w_dt   = 21495808;              // 2048*128 bf16
  const size_t o_w_out  = 22020096;              // 2048*2048 bf16
  const size_t o_w_gate = 30408704;              // 5632*2048 bf16
  const size_t o_w_up   = 53477376;              // 5632*2048 bf16
  const size_t o_w_down = 76546048;              // 2048*5632 bf16
  const size_t o_u      = 99614720;              // 2048*2048 bf16 (alias: xn, scan H0)
  const size_t o_zx     = 108003328;             // 2048*5248 f32  (alias: gate bf16)
  const size_t o_dtraw  = 150994944;             // 2048*128 bf16
  const size_t o_dtbuf  = 151519232;             // 2048*2048 f32  (alias: hsig bf16, spills into yg)
  const size_t o_yg     = 168296448;             // 2048*2048 bf16
  const size_t o_h      = 176685056;             // 2048*2048 f32  (alias: scan hpart+aprod)
  // total = 193462272 bytes

  unsigned short* w_in   = (unsigned short*)(ws + o_w_in);
  unsigned short* w_dt   = (unsigned short*)(ws + o_w_dt);
  unsigned short* w_out  = (unsigned short*)(ws + o_w_out);
  unsigned short* w_gate = (unsigned short*)(ws + o_w_gate);
  unsigned short* w_up   = (unsigned short*)(ws + o_w_up);
  unsigned short* w_down = (unsigned short*)(ws + o_w_down);
  unsigned short* u_bf   = (unsigned short*)(ws + o_u);
  unsigned short* xn_bf  = (unsigned short*)(ws + o_u);      // alias (u dead)
  float*          zxb    = (float*)(ws + o_zx);
  unsigned short* gate_b = (unsigned short*)(ws + o_zx);     // alias (zx dead)
  unsigned short* dtraw  = (unsigned short*)(ws + o_dtraw);
  float*          dtbuf  = (float*)(ws + o_dtbuf);
  unsigned short* hsig   = (unsigned short*)(ws + o_dtbuf);  // alias (dtbuf+yg dead)
  unsigned short* yg     = (unsigned short*)(ws + o_yg);
  float*          hbuf   = (float*)(ws + o_h);
  // scan scratch: hpart+aprod (8.39 MB each) exactly fill hbuf's 16.78 MB
  // region (hbuf written only at step 7, after the scan). H0 (8.39 MB)
  // exactly fills u_bf's region (u dead after step 3; xn written step 8).
  float* hpart = (float*)(ws + o_h);
  float* aprod = (float*)(ws + o_h + 8388608);
  float* H0buf = (float*)(ws + o_u);

  auto cvt = [&](const float* src, unsigned short* dst, size_t n) {
    int n2 = (int)(n / 2);
    cvt_bf16<<<(n2 + 255) / 256, 256, 0, stream>>>((const float2*)src,
                                                   (unsigned int*)dst, n2);
  };

  // 1. weights -> bf16
  cvt(in_proj_w, w_in, (size_t)5248 * 2048);
  cvt(dt_proj_w, w_dt, (size_t)2048 * 128);
  cvt(out_proj_w, w_out, (size_t)2048 * 2048);
  cvt(gate_w, w_gate, (size_t)5632 * 2048);
  cvt(up_w, w_up, (size_t)5632 * 2048);
  cvt(down_w, w_down, (size_t)2048 * 5632);

  // 2. u = rmsnorm(hidden, norm1) -> bf16
  rmsnorm_cast<<<2048, 256, 0, stream>>>(hidden, norm1_w, u_bf);

  // 3. zxbcdt = u @ in_proj_w^T   [2048, 5248] f32
  gemm_bt<0><<<dim3(5248 / 128, 16), 256, 0, stream>>>(
      u_bf, w_in, zxb, nullptr, nullptr, nullptr, 5248, 2048);

  // 4. dt_raw slice -> bf16
  cast_dtraw<<<1024, 256, 0, stream>>>(zxb, dtraw);

  // 5. dt = softplus(dt_raw @ dt_proj_w^T + b)  [2048, 2048] f32
  gemm_bt<1><<<dim3(16, 16), 256, 0, stream>>>(
      dtraw, w_dt, dtbuf, nullptr, dt_proj_b, nullptr, 2048, 128);

  // 6. chunked selective scan + D-skip + silu(z) gate -> yg bf16
  scan_partial<<<1024, 256, 0, stream>>>(zxb, dtbuf, A_log, hpart, aprod);
  scan_combine<<<512, 256, 0, stream>>>(hpart, aprod, H0buf);
  scan_final<<<1024, 256, 0, stream>>>(zxb, dtbuf, A_log, D_param, H0buf, yg);

  // 7. h = hidden + yg @ out_proj_w^T   [2048, 2048] f32
  gemm_bt<2><<<dim3(16, 16), 256, 0, stream>>>(
      yg, w_out, hbuf, nullptr, hidden, nullptr, 2048, 2048);

  // 8. xn = rmsnorm(h, norm2) -> bf16
  rmsnorm_cast<<<2048, 256, 0, stream>>>(hbuf, norm2_w, xn_bf);

  // 9. gate = xn @ gate_w^T -> bf16
  gemm_bt<3><<<dim3(5632 / 128, 16), 256, 0, stream>>>(
      xn_bf, w_gate, nullptr, gate_b, nullptr, nullptr, 5632, 2048);

  // 10. hsig = silu(gate) * (xn @ up_w^T) -> bf16
  gemm_bt<4><<<dim3(5632 / 128, 16), 256, 0, stream>>>(
      xn_bf, w_up, nullptr, hsig, nullptr, gate_b, 5632, 2048);

  // 11. out = h + hsig @ down_w^T
  gemm_bt<2><<<dim3(16, 16), 256, 0, stream>>>(
      hsig, w_down, out, nullptr, hbuf, nullptr, 2048, 5632);
}